// Round 10
// baseline (240.464 us; speedup 1.0000x reference)
//
#include <hip/hip_runtime.h>
#include <hip/hip_bf16.h>
#include <hip/hip_fp16.h>

// Problem constants
#define B_  2
#define N_  1024
#define D_  256
#define E_  64
#define H_  8
#define HS_ 64
#define FF_ 1024
#define R_  (B_*N_)   // 2048 rows (b,n)

typedef short bf8 __attribute__((ext_vector_type(8)));   // 8 bf16 (bit pattern) = 4 VGPRs
typedef float f4  __attribute__((ext_vector_type(4)));

static __device__ __forceinline__ ushort f2b(float f) {
  __hip_bfloat16 h = __float2bfloat16(f);
  return *reinterpret_cast<ushort*>(&h);
}

static __device__ __forceinline__ ushort f2h(float f) {
  __half h = __float2half(f);
  return *reinterpret_cast<ushort*>(&h);
}

static __device__ __forceinline__ float h2f(ushort u) {
  __half h = *reinterpret_cast<__half*>(&u);
  return __half2float(h);
}

// ---------------- fused weight pack (all bf16, B-matrices TRANSPOSED [N][K]) ----------------
__global__ void k_pack(const float* __restrict__ node, const float* __restrict__ Wq,
                       const float* __restrict__ Wk, const float* __restrict__ Wv,
                       const float* __restrict__ Wp, const float* __restrict__ W1,
                       const float* __restrict__ W2,
                       ushort* __restrict__ node_bf, ushort* __restrict__ wqkvT,
                       ushort* __restrict__ wkeT, ushort* __restrict__ wpT,
                       ushort* __restrict__ w1T, ushort* __restrict__ w2T) {
  int idx = blockIdx.x * 256 + threadIdx.x;
  if (idx < 524288) {                       // node -> bf16
    node_bf[idx] = f2b(node[idx]);
    return;
  }
  idx -= 524288;
  if (idx < 393216) {                       // wqkvT[c][i], c in [0,1536), K=256
    int c = idx >> 8, i = idx & 255;
    int mat = c >> 9, h = (c >> 6) & 7, o = c & 63;
    float v;
    if (mat == 0)      v = Wq[(h * 256 + i) * 64 + o] * 0.125f;   // q scaled 1/sqrt(HS)
    else if (mat == 1) v = Wk[(h * 320 + i) * 64 + o];            // Wk: [H][320][64]
    else               v = Wv[(h * 256 + i) * 64 + o];
    wqkvT[idx] = f2b(v);
    return;
  }
  idx -= 393216;
  if (idx < 262144) {                       // wkeT[c=h2*64+e][r=h*64+o]  (block-diagonal)
    int c = idx >> 9, r = idx & 511;
    int h2 = c >> 6, e = c & 63, h = r >> 6, o = r & 63;
    wkeT[idx] = (h2 == h) ? f2b(Wk[(h * 320 + 256 + e) * 64 + o]) : (ushort)0;
    return;
  }
  idx -= 262144;
  if (idx < 131072) {                       // wpT[c][r], c in [0,256), r = h*64+i
    int c = idx >> 9, r = idx & 511;
    wpT[idx] = f2b(Wp[r * 256 + c]);
    return;
  }
  idx -= 131072;
  if (idx < 262144) {                       // w1T[c][k], c in [0,1024), K=256
    int c = idx >> 8, k = idx & 255;
    w1T[idx] = f2b(W1[k * 1024 + c]);
    return;
  }
  idx -= 262144;
  {                                         // w2T[c][k], c in [0,256), K=1024
    int c = idx >> 10, k = idx & 1023;
    w2T[idx] = f2b(W2[k * 256 + c]);
  }
}

// vT[b][h][o][m] <- qkv[(b*1024+m)*1536 + 1024 + h*64 + o]   (B^T panel for attn@v)
__global__ void k_vT(const ushort* __restrict__ qkv, ushort* __restrict__ vt) {
  int idx = blockIdx.x * 256 + threadIdx.x;   // 16*64*1024
  if (idx >= 16 * 64 * 1024) return;
  int m = idx & 1023;
  int rest = idx >> 10;
  int o = rest & 63;
  int bh = rest >> 6;
  int b = bh >> 3, h = bh & 7;
  vt[idx] = qkv[(size_t)(b * 1024 + m) * 1536 + 1024 + h * 64 + o];
}

// ---------------- generic bf16 MFMA GEMM, B pre-transposed ----------------
// C[M x N] = A[M x K] @ B[K x N];  Bt is B^T, row-major [N][K] with stride ldbt.
// EPI: 0=none, 2=+bias, 3=+bias,relu   OFMT: 0=f32, 1=bf16, 2=f16
// NBT: 64-col tiles per block (block = 64 x 64*NBT)
// BDIAG: B block-diagonal with 64x64 blocks -> K-loop restricted to [c0, c0+64)
// Batched via blockIdx.z: offset = (z>>3)*s1 + (z&7)*s2  (element offsets)
template<int EPI, int OFMT, int NBT, bool BDIAG>
__global__ void k_gemm(const ushort* __restrict__ A, const ushort* __restrict__ Bt,
                       void* __restrict__ Cv, const float* __restrict__ bias,
                       int M, int N, int K, int lda, int ldbt, int ldc,
                       long long as1, long long as2, long long bs1, long long bs2,
                       long long cs1, long long cs2) {
  int z = blockIdx.z;
  const ushort* Ab = A  + (size_t)((z >> 3) * as1 + (z & 7) * as2);
  const ushort* Bb = Bt + (size_t)((z >> 3) * bs1 + (z & 7) * bs2);
  size_t coff = (size_t)((z >> 3) * cs1 + (z & 7) * cs2);
  int r0 = blockIdx.x * 64, c0 = blockIdx.y * (64 * NBT);

  __shared__ ushort As[64][40];          // [row][k], +8 pad
  __shared__ ushort Bs[64 * NBT][40];    // [col][k], +8 pad

  int tid = threadIdx.x;
  int lane = tid & 63, w = tid >> 6;
  int wm = w >> 1, wn = w & 1;            // wave -> 32-row half x 32-col half
  int kg = lane >> 4, lr = lane & 15;

  f4 acc[2][2 * NBT] = {};

  int kbeg = BDIAG ? c0 : 0;
  int kend = BDIAG ? c0 + 64 : K;
  for (int k0 = kbeg; k0 < kend; k0 += 32) {
    __syncthreads();
    { // stage A tile 64x32 (one 16B load per thread)
      int row = tid >> 2, ch = tid & 3;
      *(int4*)&As[row][ch * 8] = *(const int4*)(Ab + (size_t)(r0 + row) * lda + k0 + ch * 8);
    }
    #pragma unroll
    for (int i = 0; i < NBT; ++i) { // stage Bt tile 64*NBT x 32
      int row = (tid >> 2) + 64 * i, ch = tid & 3;
      *(int4*)&Bs[row][ch * 8] = *(const int4*)(Bb + (size_t)(c0 + row) * ldbt + k0 + ch * 8);
    }
    __syncthreads();

    bf8 bfr[2 * NBT];
    #pragma unroll
    for (int nt = 0; nt < NBT; ++nt)
      #pragma unroll
      for (int cb = 0; cb < 2; ++cb)
        bfr[nt * 2 + cb] = *(const bf8*)&Bs[nt * 64 + wn * 32 + cb * 16 + lr][kg * 8];
    #pragma unroll
    for (int rb = 0; rb < 2; ++rb) {
      bf8 af = *(const bf8*)&As[wm * 32 + rb * 16 + lr][kg * 8];     // A: row=l&15, k=8*kg+j
      #pragma unroll
      for (int q = 0; q < 2 * NBT; ++q)
        acc[rb][q] = __builtin_amdgcn_mfma_f32_16x16x32_bf16(af, bfr[q], acc[rb][q], 0, 0, 0);
    }
  }

  float*  Cf = (float*)Cv;
  ushort* Cb = (ushort*)Cv;
  __half* Ch = (__half*)Cv;
  #pragma unroll
  for (int rb = 0; rb < 2; ++rb) {
    #pragma unroll
    for (int q = 0; q < 2 * NBT; ++q) {
      #pragma unroll
      for (int rr = 0; rr < 4; ++rr) {
        int row = r0 + wm * 32 + rb * 16 + kg * 4 + rr;   // D: col=l&15, row=4*kg+reg
        int col = c0 + (q >> 1) * 64 + wn * 32 + (q & 1) * 16 + lr;
        size_t ci = coff + (size_t)row * ldc + col;
        float v = acc[rb][q][rr];
        if (EPI >= 2) v += bias[col];
        if (EPI == 3) v = fmaxf(v, 0.0f);
        if (OFMT == 1)      Cb[ci] = f2b(v);
        else if (OFMT == 2) Ch[ci] = __float2half(v);
        else                Cf[ci] = v;
      }
    }
  }
}

// ---------------- fused edge-logits (MFMA) + node-logits + softmax -> bf16 attn ----------------
// No LDS staging of edge: each edge element feeds exactly one lane of one MFMA
// (zero reuse), so lanes load their A-fragments straight from global (2x float4,
// 128B-aligned fully-used segments), cvt to bf16 in regs, MFMA. No main-loop barriers.
__global__ __launch_bounds__(256, 6) void k_fused(
    const float* __restrict__ edge, const float* __restrict__ qe,
    const __half* __restrict__ logN, ushort* __restrict__ attn) {
  int bid = blockIdx.x;            // b*1024 + n
  int b = bid >> 10, n = bid & 1023;
  int t = threadIdx.x;
  int lane = t & 63, w = t >> 6;
  int kg = lane >> 4, lr = lane & 15;

  __shared__ ushort lg[8][1032];   // block logits [h][m] fp16, +8 pad (16.5 KB)
  __shared__ float red[2][4][8];

  // ---- B fragments (qe row -> bf16), built once, kept in 8 VGPRs ----
  bf8 bq[2];
  {
    const float* qrow = qe + (size_t)bid * 512 + (size_t)(lr & 7) * 64;
    #pragma unroll
    for (int kk = 0; kk < 2; ++kk) {
      float4 a  = *reinterpret_cast<const float4*>(&qrow[kk * 32 + kg * 8]);
      float4 c4 = *reinterpret_cast<const float4*>(&qrow[kk * 32 + kg * 8 + 4]);
      bq[kk][0] = (short)f2b(a.x);  bq[kk][1] = (short)f2b(a.y);
      bq[kk][2] = (short)f2b(a.z);  bq[kk][3] = (short)f2b(a.w);
      bq[kk][4] = (short)f2b(c4.x); bq[kk][5] = (short)f2b(c4.y);
      bq[kk][6] = (short)f2b(c4.z); bq[kk][7] = (short)f2b(c4.w);
    }
  }

  const float* eb = edge + (size_t)bid * 65536;   // 1024 rows x 64 floats

  // wave w owns rows [w*256, w*256+256): 16 sub-tiles of 16 m-rows, no barriers
  #pragma unroll 4
  for (int st = 0; st < 16; ++st) {
    int sr = w * 256 + st * 16 + lr;              // this lane's A row
    f4 acc = {};
    #pragma unroll
    for (int kk = 0; kk < 2; ++kk) {
      const float* p = eb + (size_t)sr * 64 + kk * 32 + kg * 8;
      float4 a  = *reinterpret_cast<const float4*>(p);
      float4 c4 = *reinterpret_cast<const float4*>(p + 4);
      bf8 af;
      af[0] = (short)f2b(a.x);  af[1] = (short)f2b(a.y);
      af[2] = (short)f2b(a.z);  af[3] = (short)f2b(a.w);
      af[4] = (short)f2b(c4.x); af[5] = (short)f2b(c4.y);
      af[6] = (short)f2b(c4.z); af[7] = (short)f2b(c4.w);
      acc = __builtin_amdgcn_mfma_f32_16x16x32_bf16(af, bq[kk], acc, 0, 0, 0);
    }
    if (lr < 8) {                                 // D: col=l&15 (=h), row=4*kg+rr
      int mbase = w * 256 + st * 16 + kg * 4;
      uint2 pk;
      pk.x = (uint)f2h(acc[0]) | ((uint)f2h(acc[1]) << 16);
      pk.y = (uint)f2h(acc[2]) | ((uint)f2h(acc[3]) << 16);
      *reinterpret_cast<uint2*>(&lg[lr][mbase]) = pk;   // one 8B write for 4 m's
    }
  }

  // issue node-logit loads BEFORE the barrier (ushort4 = 8B/lane, m = 4t..4t+3)
  ushort4 lNr[8];
  #pragma unroll
  for (int h = 0; h < 8; ++h)
    lNr[h] = *reinterpret_cast<const ushort4*>(
        &reinterpret_cast<const ushort*>(logN)[((size_t)(b * 8 + h) * 1024 + n) * 1024 + 4 * t]);
  __syncthreads();                 // lg complete

  // ---- softmax: thread owns m = 4t + j ----
  float l[4][8];
  #pragma unroll
  for (int h = 0; h < 8; ++h) {
    ushort4 lv = *reinterpret_cast<const ushort4*>(&lg[h][4 * t]);
    l[0][h] = h2f(lv.x) + h2f(lNr[h].x);
    l[1][h] = h2f(lv.y) + h2f(lNr[h].y);
    l[2][h] = h2f(lv.z) + h2f(lNr[h].z);
    l[3][h] = h2f(lv.w) + h2f(lNr[h].w);
  }
  float mx[8], sm[8];
  #pragma unroll
  for (int h = 0; h < 8; ++h) {
    float v = fmaxf(fmaxf(l[0][h], l[1][h]), fmaxf(l[2][h], l[3][h]));
    #pragma unroll
    for (int off = 32; off; off >>= 1) v = fmaxf(v, __shfl_xor(v, off));
    if (lane == 0) red[0][w][h] = v;
  }
  __syncthreads();
  #pragma unroll
  for (int h = 0; h < 8; ++h)
    mx[h] = fmaxf(fmaxf(red[0][0][h], red[0][1][h]), fmaxf(red[0][2][h], red[0][3][h]));
  #pragma unroll
  for (int j = 0; j < 4; ++j)
    #pragma unroll
    for (int h = 0; h < 8; ++h)
      l[j][h] = __expf(l[j][h] - mx[h]);
  #pragma unroll
  for (int h = 0; h < 8; ++h) {
    float v = l[0][h] + l[1][h] + l[2][h] + l[3][h];
    #pragma unroll
    for (int off = 32; off; off >>= 1) v += __shfl_xor(v, off);
    if (lane == 0) red[1][w][h] = v;
  }
  __syncthreads();
  #pragma unroll
  for (int h = 0; h < 8; ++h)
    sm[h] = 1.0f / (red[1][0][h] + red[1][1][h] + red[1][2][h] + red[1][3][h]);
  #pragma unroll
  for (int h = 0; h < 8; ++h) {
    size_t base = ((size_t)(b * 8 + h) * 1024 + n) * 1024;
    ushort4 o;
    o.x = f2b(l[0][h] * sm[h]);
    o.y = f2b(l[1][h] * sm[h]);
    o.z = f2b(l[2][h] * sm[h]);
    o.w = f2b(l[3][h] * sm[h]);
    *reinterpret_cast<ushort4*>(&attn[base + 4 * t]) = o;   // 8B/lane store
  }
}

// ---------------- residual + layernorm (D=256, one block per row) ----------------
__global__ void k_ln(const float* __restrict__ a, const float* __restrict__ bb,
                     const float* __restrict__ g, const float* __restrict__ be,
                     float* __restrict__ of, ushort* __restrict__ ob) {
  int r = blockIdx.x, i = threadIdx.x;
  float t = a[(size_t)r * 256 + i] + bb[(size_t)r * 256 + i];
  __shared__ float red[4];

  float s = t;
  for (int off = 32; off; off >>= 1) s += __shfl_xor(s, off);
  if ((i & 63) == 0) red[i >> 6] = s;
  __syncthreads();
  float mean = (red[0] + red[1] + red[2] + red[3]) * (1.0f / 256.0f);
  __syncthreads();

  float d = t - mean;
  float q = d * d;
  for (int off = 32; off; off >>= 1) q += __shfl_xor(q, off);
  if ((i & 63) == 0) red[i >> 6] = q;
  __syncthreads();
  float var = (red[0] + red[1] + red[2] + red[3]) * (1.0f / 256.0f);

  float y = d * rsqrtf(var + 1e-6f) * g[i] + be[i];
  of[(size_t)r * 256 + i] = y;
  if (ob) ob[(size_t)r * 256 + i] = f2b(y);
}

// ---------------- launch ----------------

extern "C" void kernel_launch(void* const* d_in, const int* in_sizes, int n_in,
                              void* d_out, int out_size, void* d_ws, size_t ws_size,
                              hipStream_t stream) {
  (void)in_sizes; (void)n_in; (void)out_size; (void)ws_size;
  const float* node = (const float*)d_in[0];
  const float* edge = (const float*)d_in[1];
  const float* Wq   = (const float*)d_in[2];
  const float* Wk   = (const float*)d_in[3];
  const float* Wv   = (const float*)d_in[4];
  const float* Wp   = (const float*)d_in[5];
  const float* bp   = (const float*)d_in[6];
  const float* g1   = (const float*)d_in[7];
  const float* be1  = (const float*)d_in[8];
  const float* W1   = (const float*)d_in[9];
  const float* b1   = (const float*)d_in[10];
  const float* W2   = (const float*)d_in[11];
  const float* b2   = (const float*)d_in[12];
  const float* g2   = (const float*)d_in[13];
  const float* be2  = (const float*)d_in[14];
  float* out = (float*)d_out;

  char* ws = (char*)d_ws;
  size_t off = 0;
  auto alloc = [&](size_t bytes) -> char* {
    char* p = ws + off;
    off = (off + bytes + 255) & ~(size_t)255;
    return p;
  };
  ushort* node_bf = (ushort*)alloc((size_t)R_ * D_ * 2);
  ushort* wqkvT   = (ushort*)alloc((size_t)1536 * 256 * 2);
  ushort* wkeT    = (ushort*)alloc((size_t)512 * 512 * 2);
  ushort* wpT     = (ushort*)alloc((size_t)256 * 512 * 2);
  ushort* w1T     = (ushort*)alloc((size_t)1024 * 256 * 2);
  ushort* w2T     = (ushort*)alloc((size_t)256 * 1024 * 2);
  ushort* qkv     = (ushort*)alloc((size_t)R_ * 1536 * 2);        // 6 MiB
  float*  qe      = (float*) alloc((size_t)R_ * 512 * 4);         // 4 MiB
  ushort* vt      = (ushort*)alloc((size_t)16 * 64 * 1024 * 2);   // 2 MiB
  __half* logits  = (__half*)alloc((size_t)16 * 1024 * 1024 * 2); // 32 MiB fp16
  ushort* attn    = (ushort*)alloc((size_t)16 * 1024 * 1024 * 2); // 32 MiB
  ushort* mo      = (ushort*)alloc((size_t)R_ * 512 * 2);
  float*  mha     = (float*) alloc((size_t)R_ * 256 * 4);
  float*  xf      = (float*) alloc((size_t)R_ * 256 * 4);
  ushort* xb      = (ushort*)alloc((size_t)R_ * 256 * 2);
  ushort* hb      = (ushort*)alloc((size_t)R_ * 1024 * 2);
  float*  ff      = (float*) alloc((size_t)R_ * 256 * 4);

  // --- single fused pack ---
  k_pack<<<dim3(7168), dim3(256), 0, stream>>>(node, Wq, Wk, Wv, Wp, W1, W2,
                                               node_bf, wqkvT, wkeT, wpT, w1T, w2T);

  // --- qkv = node @ Wqkv (bf16 out, q pre-scaled) ---
  k_gemm<0, 1, 1, false><<<dim3(32, 24, 1), dim3(256), 0, stream>>>(
      node_bf, wqkvT, qkv, nullptr, 2048, 1536, 256, 256, 256, 1536,
      0LL, 0LL, 0LL, 0LL, 0LL, 0LL);

  // --- qe = q @ blockdiag(WkE^T)  (fp32 out; BDIAG skips the zero K-blocks) ---
  k_gemm<0, 0, 1, true><<<dim3(32, 8, 1), dim3(256), 0, stream>>>(
      qkv, wkeT, qe, nullptr, 2048, 512, 512, 1536, 512, 512,
      0LL, 0LL, 0LL, 0LL, 0LL, 0LL);

  // --- vT pack (for attn@v B-panel) ---
  k_vT<<<dim3(4096), dim3(256), 0, stream>>>(qkv, vt);

  // --- node logits = q @ kn^T  (batched over (b,h); 64x256 tiles; fp16 out) ---
  k_gemm<0, 2, 4, false><<<dim3(16, 4, 16), dim3(256), 0, stream>>>(
      qkv, qkv + 512, logits, nullptr, 1024, 1024, 64, 1536, 1536, 1024,
      1572864LL, 64LL, 1572864LL, 64LL, 8388608LL, 1048576LL);

  // --- fused: edge MFMA dot (direct-from-global) + node logits + softmax -> bf16 attn ---
  k_fused<<<dim3(2048), dim3(256), 0, stream>>>(edge, qe, logits, attn);

  // --- mo = attn @ v  (batched; Bt = vT; bf16 out as [b][n][h*64+o]) ---
  k_gemm<0, 1, 1, false><<<dim3(16, 1, 16), dim3(256), 0, stream>>>(
      attn, vt, mo, nullptr, 1024, 64, 1024, 1024, 1024, 512,
      8388608LL, 1048576LL, 524288LL, 65536LL, 524288LL, 64LL);

  // --- mha = mo @ Wp + bp  (fp32) ---
  k_gemm<2, 0, 1, false><<<dim3(32, 4, 1), dim3(256), 0, stream>>>(
      mo, wpT, mha, bp, 2048, 256, 512, 512, 512, 256,
      0LL, 0LL, 0LL, 0LL, 0LL, 0LL);

  // --- x = LN1(node + mha) -> xf (fp32), xb (bf16) ---
  k_ln<<<dim3(2048), dim3(256), 0, stream>>>(node, mha, g1, be1, xf, xb);

  // --- ffn hidden = relu(x @ W1 + b1)  (bf16) ---
  k_gemm<3, 1, 1, false><<<dim3(32, 16, 1), dim3(256), 0, stream>>>(
      xb, w1T, hb, b1, 2048, 1024, 256, 256, 256, 1024,
      0LL, 0LL, 0LL, 0LL, 0LL, 0LL);

  // --- ff = hidden @ W2 + b2  (fp32) ---
  k_gemm<2, 0, 1, false><<<dim3(32, 4, 1), dim3(256), 0, stream>>>(
      hb, w2T, ff, b2, 2048, 256, 1024, 1024, 1024, 256,
      0LL, 0LL, 0LL, 0LL, 0LL, 0LL);

  // --- out = LN2(x + ff)  (fp32 to d_out) ---
  k_ln<<<dim3(2048), dim3(256), 0, stream>>>(xf, ff, g2, be2, out, nullptr);
}

// Round 11
// 236.102 us; speedup vs baseline: 1.0185x; 1.0185x over previous
//
#include <hip/hip_runtime.h>
#include <hip/hip_bf16.h>
#include <hip/hip_fp16.h>

// Problem constants
#define B_  2
#define N_  1024
#define D_  256
#define E_  64
#define H_  8
#define HS_ 64
#define FF_ 1024
#define R_  (B_*N_)   // 2048 rows (b,n)

typedef short bf8 __attribute__((ext_vector_type(8)));   // 8 bf16 (bit pattern) = 4 VGPRs
typedef float f4  __attribute__((ext_vector_type(4)));

static __device__ __forceinline__ ushort f2b(float f) {
  __hip_bfloat16 h = __float2bfloat16(f);
  return *reinterpret_cast<ushort*>(&h);
}

static __device__ __forceinline__ ushort f2h(float f) {
  __half h = __float2half(f);
  return *reinterpret_cast<ushort*>(&h);
}

static __device__ __forceinline__ float h2f(ushort u) {
  __half h = *reinterpret_cast<__half*>(&u);
  return __half2float(h);
}

static __device__ __forceinline__ ushort4 f4_to_b4(float4 v) {
  ushort4 r;
  r.x = f2b(v.x); r.y = f2b(v.y); r.z = f2b(v.z); r.w = f2b(v.w);
  return r;
}

// ---------------- fused weight pack (all bf16, B-matrices TRANSPOSED [N][K]) ----------------
// regions: node_bf 524288 | wqkvT 393216 | wpT 131072 | w1T 262144 | w2T 262144 | wqeT 131072
// wqeT[c=h*64+e][i] = sum_o Wq[h][i][o] * WkE[h][e][o] / 8   (qe folded into qkv GEMM)
__global__ void k_pack(const float* __restrict__ node, const float* __restrict__ Wq,
                       const float* __restrict__ Wk, const float* __restrict__ Wv,
                       const float* __restrict__ Wp, const float* __restrict__ W1,
                       const float* __restrict__ W2,
                       ushort* __restrict__ node_bf, ushort* __restrict__ wqkvT,
                       ushort* __restrict__ wpT, ushort* __restrict__ w1T,
                       ushort* __restrict__ w2T, ushort* __restrict__ wqeT) {
  int idx = blockIdx.x * 256 + threadIdx.x;
  if (idx < 524288) {                       // node -> bf16
    node_bf[idx] = f2b(node[idx]);
    return;
  }
  idx -= 524288;
  if (idx < 393216) {                       // wqkvT[c][i], c in [0,1536), K=256
    int c = idx >> 8, i = idx & 255;
    int mat = c >> 9, h = (c >> 6) & 7, o = c & 63;
    float v;
    if (mat == 0)      v = Wq[(h * 256 + i) * 64 + o] * 0.125f;   // q scaled 1/sqrt(HS)
    else if (mat == 1) v = Wk[(h * 320 + i) * 64 + o];            // Wk: [H][320][64]
    else               v = Wv[(h * 256 + i) * 64 + o];
    wqkvT[idx] = f2b(v);
    return;
  }
  idx -= 393216;
  if (idx < 131072) {                       // wpT[c][r], c in [0,256), r = h*64+i
    int c = idx >> 9, r = idx & 511;
    wpT[idx] = f2b(Wp[r * 256 + c]);
    return;
  }
  idx -= 131072;
  if (idx < 262144) {                       // w1T[c][k], c in [0,1024), K=256
    int c = idx >> 8, k = idx & 255;
    w1T[idx] = f2b(W1[k * 1024 + c]);
    return;
  }
  idx -= 262144;
  if (idx < 262144) {                       // w2T[c][k], c in [0,256), K=1024
    int c = idx >> 10, k = idx & 1023;
    w2T[idx] = f2b(W2[k * 256 + c]);
    return;
  }
  idx -= 262144;
  {                                         // wqeT[c=h*64+e][i]: 64-term dot (L2-resident)
    int c = idx >> 8, i = idx & 255;
    int h = c >> 6, e = c & 63;
    const float* wq = Wq + (size_t)(h * 256 + i) * 64;
    const float* we = Wk + (size_t)(h * 320 + 256 + e) * 64;
    float s = 0.f;
    #pragma unroll 8
    for (int o = 0; o < 64; ++o) s += wq[o] * we[o];
    wqeT[idx] = f2b(s * 0.125f);
  }
}

// vT[b][h][o][m] <- qkv[(b*1024+m)*2048 + 1024 + h*64 + o]   (B^T panel for attn@v)
__global__ void k_vT(const ushort* __restrict__ qkv, ushort* __restrict__ vt) {
  int idx = blockIdx.x * 256 + threadIdx.x;   // 16*64*1024
  if (idx >= 16 * 64 * 1024) return;
  int m = idx & 1023;
  int rest = idx >> 10;
  int o = rest & 63;
  int bh = rest >> 6;
  int b = bh >> 3, h = bh & 7;
  vt[idx] = qkv[(size_t)(b * 1024 + m) * 2048 + 1024 + h * 64 + o];
}

// ---------------- generic bf16 MFMA GEMM, B pre-transposed ----------------
// C[M x N] = A[M x K] @ B[K x N];  Bt is B^T, row-major [N][K] with stride ldbt.
// EPI: 0=none, 2=+bias, 3=+bias,relu   OFMT: 0=f32, 1=bf16, 2=f16
// NBT: 64-col tiles per block (block = 64 x 64*NBT)
// Batched via blockIdx.z: offset = (z>>3)*s1 + (z&7)*s2  (element offsets)
template<int EPI, int OFMT, int NBT>
__global__ void k_gemm(const ushort* __restrict__ A, const ushort* __restrict__ Bt,
                       void* __restrict__ Cv, const float* __restrict__ bias,
                       int M, int N, int K, int lda, int ldbt, int ldc,
                       long long as1, long long as2, long long bs1, long long bs2,
                       long long cs1, long long cs2) {
  int z = blockIdx.z;
  const ushort* Ab = A  + (size_t)((z >> 3) * as1 + (z & 7) * as2);
  const ushort* Bb = Bt + (size_t)((z >> 3) * bs1 + (z & 7) * bs2);
  size_t coff = (size_t)((z >> 3) * cs1 + (z & 7) * cs2);
  int r0 = blockIdx.x * 64, c0 = blockIdx.y * (64 * NBT);

  __shared__ ushort As[64][40];          // [row][k], +8 pad
  __shared__ ushort Bs[64 * NBT][40];    // [col][k], +8 pad

  int tid = threadIdx.x;
  int lane = tid & 63, w = tid >> 6;
  int wm = w >> 1, wn = w & 1;            // wave -> 32-row half x 32-col half
  int kg = lane >> 4, lr = lane & 15;

  f4 acc[2][2 * NBT] = {};

  for (int k0 = 0; k0 < K; k0 += 32) {
    __syncthreads();
    { // stage A tile 64x32 (one 16B load per thread)
      int row = tid >> 2, ch = tid & 3;
      *(int4*)&As[row][ch * 8] = *(const int4*)(Ab + (size_t)(r0 + row) * lda + k0 + ch * 8);
    }
    #pragma unroll
    for (int i = 0; i < NBT; ++i) { // stage Bt tile 64*NBT x 32
      int row = (tid >> 2) + 64 * i, ch = tid & 3;
      *(int4*)&Bs[row][ch * 8] = *(const int4*)(Bb + (size_t)(c0 + row) * ldbt + k0 + ch * 8);
    }
    __syncthreads();

    bf8 bfr[2 * NBT];
    #pragma unroll
    for (int nt = 0; nt < NBT; ++nt)
      #pragma unroll
      for (int cb = 0; cb < 2; ++cb)
        bfr[nt * 2 + cb] = *(const bf8*)&Bs[nt * 64 + wn * 32 + cb * 16 + lr][kg * 8];
    #pragma unroll
    for (int rb = 0; rb < 2; ++rb) {
      bf8 af = *(const bf8*)&As[wm * 32 + rb * 16 + lr][kg * 8];     // A: row=l&15, k=8*kg+j
      #pragma unroll
      for (int q = 0; q < 2 * NBT; ++q)
        acc[rb][q] = __builtin_amdgcn_mfma_f32_16x16x32_bf16(af, bfr[q], acc[rb][q], 0, 0, 0);
    }
  }

  float*  Cf = (float*)Cv;
  ushort* Cb = (ushort*)Cv;
  __half* Ch = (__half*)Cv;
  #pragma unroll
  for (int rb = 0; rb < 2; ++rb) {
    #pragma unroll
    for (int q = 0; q < 2 * NBT; ++q) {
      #pragma unroll
      for (int rr = 0; rr < 4; ++rr) {
        int row = r0 + wm * 32 + rb * 16 + kg * 4 + rr;   // D: col=l&15, row=4*kg+reg
        int col = c0 + (q >> 1) * 64 + wn * 32 + (q & 1) * 16 + lr;
        size_t ci = coff + (size_t)row * ldc + col;
        float v = acc[rb][q][rr];
        if (EPI >= 2) v += bias[col];
        if (EPI == 3) v = fmaxf(v, 0.0f);
        if (OFMT == 1)      Cb[ci] = f2b(v);
        else if (OFMT == 2) Ch[ci] = __float2half(v);
        else                Cf[ci] = v;
      }
    }
  }
}

// ---------------- fused edge-logits (MFMA) + node-logits + softmax -> bf16 attn ----------------
// R9 structure (proven best): LDS-staged edge stream w/ reg prefetch, swizzled bf16 tile,
// lg[8][1032] fp16 logits, vectorized epilogue. qe now read as bf16 (from qkv col 1536).
__global__ __launch_bounds__(256, 4) void k_fused(
    const float* __restrict__ edge, const ushort* __restrict__ qe, int ldqe,
    const __half* __restrict__ logN, ushort* __restrict__ attn) {
  int bid = blockIdx.x;            // b*1024 + n
  int b = bid >> 10, n = bid & 1023;
  int t = threadIdx.x;
  int lane = t & 63, w = t >> 6;
  int kg = lane >> 4, lr = lane & 15;

  __shared__ ushort As[128 * 64];  // 16 KB bf16 stage, slot^(row&7) swizzle
  __shared__ ushort lg[8][1032];   // block logits [h][m] fp16, +8 pad (16.5 KB)
  __shared__ float red[2][4][8];

  // ---- B fragments (qe row, already bf16), 8 VGPRs ----
  bf8 bq[2];
  {
    const ushort* qrow = qe + (size_t)bid * ldqe + (size_t)(lr & 7) * 64;
    bq[0] = *reinterpret_cast<const bf8*>(&qrow[kg * 8]);
    bq[1] = *reinterpret_cast<const bf8*>(&qrow[32 + kg * 8]);
  }

  const float* eb = edge + (size_t)bid * 65536;   // 1024 rows x 64 floats

  // prefetch tile 0 (8 float4/thread, fully coalesced)
  float4 pf[8];
  #pragma unroll
  for (int u = 0; u < 8; ++u)
    pf[u] = reinterpret_cast<const float4*>(eb)[t + 256 * u];

  #pragma unroll 1
  for (int tl = 0; tl < 8; ++tl) {
    __syncthreads();               // prev tile's A-frag reads done
    #pragma unroll
    for (int u = 0; u < 8; ++u) {  // cvt fp32->bf16, swizzled write: slot ^= row&7
      int g = t + 256 * u;
      int rl = g >> 4, c = t & 15;          // row 0..127, float4-slot 0..15
      int slot = (c >> 1) ^ (rl & 7), half = c & 1;
      *reinterpret_cast<ushort4*>(&As[rl * 64 + slot * 8 + half * 4]) = f4_to_b4(pf[u]);
    }
    if (tl < 7) {                  // issue next tile's loads; hide under compute
      const float4* src = reinterpret_cast<const float4*>(eb + (tl + 1) * 8192);
      #pragma unroll
      for (int u = 0; u < 8; ++u) pf[u] = src[t + 256 * u];
    }
    __syncthreads();               // stage visible

    // wave w owns stage rows [w*32, w*32+32): 2 sub-tiles of 16 m
    #pragma unroll
    for (int sub = 0; sub < 2; ++sub) {
      int sr = w * 32 + sub * 16 + lr;      // A row in stage
      f4 acc = {};
      #pragma unroll
      for (int kk = 0; kk < 2; ++kk) {
        bf8 af = *reinterpret_cast<const bf8*>(&As[sr * 64 + (((kk * 4 + kg) ^ (sr & 7)) << 3)]);
        acc = __builtin_amdgcn_mfma_f32_16x16x32_bf16(af, bq[kk], acc, 0, 0, 0);
      }
      if (lr < 8) {                         // D: col=l&15 (=h), row=4*kg+rr
        int mbase = tl * 128 + w * 32 + sub * 16 + kg * 4;
        uint2 pk;
        pk.x = (uint)f2h(acc[0]) | ((uint)f2h(acc[1]) << 16);
        pk.y = (uint)f2h(acc[2]) | ((uint)f2h(acc[3]) << 16);
        *reinterpret_cast<uint2*>(&lg[lr][mbase]) = pk;   // one 8B write for 4 m's
      }
    }
  }

  // issue node-logit loads BEFORE the barrier (ushort4 = 8B/lane, m = 4t..4t+3)
  ushort4 lNr[8];
  #pragma unroll
  for (int h = 0; h < 8; ++h)
    lNr[h] = *reinterpret_cast<const ushort4*>(
        &reinterpret_cast<const ushort*>(logN)[((size_t)(b * 8 + h) * 1024 + n) * 1024 + 4 * t]);
  __syncthreads();                 // lg complete

  // ---- softmax: thread owns m = 4t + j ----
  float l[4][8];
  #pragma unroll
  for (int h = 0; h < 8; ++h) {
    ushort4 lv = *reinterpret_cast<const ushort4*>(&lg[h][4 * t]);
    l[0][h] = h2f(lv.x) + h2f(lNr[h].x);
    l[1][h] = h2f(lv.y) + h2f(lNr[h].y);
    l[2][h] = h2f(lv.z) + h2f(lNr[h].z);
    l[3][h] = h2f(lv.w) + h2f(lNr[h].w);
  }
  float mx[8], sm[8];
  #pragma unroll
  for (int h = 0; h < 8; ++h) {
    float v = fmaxf(fmaxf(l[0][h], l[1][h]), fmaxf(l[2][h], l[3][h]));
    #pragma unroll
    for (int off = 32; off; off >>= 1) v = fmaxf(v, __shfl_xor(v, off));
    if (lane == 0) red[0][w][h] = v;
  }
  __syncthreads();
  #pragma unroll
  for (int h = 0; h < 8; ++h)
    mx[h] = fmaxf(fmaxf(red[0][0][h], red[0][1][h]), fmaxf(red[0][2][h], red[0][3][h]));
  #pragma unroll
  for (int j = 0; j < 4; ++j)
    #pragma unroll
    for (int h = 0; h < 8; ++h)
      l[j][h] = __expf(l[j][h] - mx[h]);
  #pragma unroll
  for (int h = 0; h < 8; ++h) {
    float v = l[0][h] + l[1][h] + l[2][h] + l[3][h];
    #pragma unroll
    for (int off = 32; off; off >>= 1) v += __shfl_xor(v, off);
    if (lane == 0) red[1][w][h] = v;
  }
  __syncthreads();
  #pragma unroll
  for (int h = 0; h < 8; ++h)
    sm[h] = 1.0f / (red[1][0][h] + red[1][1][h] + red[1][2][h] + red[1][3][h]);
  #pragma unroll
  for (int h = 0; h < 8; ++h) {
    size_t base = ((size_t)(b * 8 + h) * 1024 + n) * 1024;
    ushort4 o;
    o.x = f2b(l[0][h] * sm[h]);
    o.y = f2b(l[1][h] * sm[h]);
    o.z = f2b(l[2][h] * sm[h]);
    o.w = f2b(l[3][h] * sm[h]);
    *reinterpret_cast<ushort4*>(&attn[base + 4 * t]) = o;   // 8B/lane store
  }
}

// ---------------- residual + layernorm (D=256, one block per row) ----------------
__global__ void k_ln(const float* __restrict__ a, const float* __restrict__ bb,
                     const float* __restrict__ g, const float* __restrict__ be,
                     float* __restrict__ of, ushort* __restrict__ ob) {
  int r = blockIdx.x, i = threadIdx.x;
  float t = a[(size_t)r * 256 + i] + bb[(size_t)r * 256 + i];
  __shared__ float red[4];

  float s = t;
  for (int off = 32; off; off >>= 1) s += __shfl_xor(s, off);
  if ((i & 63) == 0) red[i >> 6] = s;
  __syncthreads();
  float mean = (red[0] + red[1] + red[2] + red[3]) * (1.0f / 256.0f);
  __syncthreads();

  float d = t - mean;
  float q = d * d;
  for (int off = 32; off; off >>= 1) q += __shfl_xor(q, off);
  if ((i & 63) == 0) red[i >> 6] = q;
  __syncthreads();
  float var = (red[0] + red[1] + red[2] + red[3]) * (1.0f / 256.0f);

  float y = d * rsqrtf(var + 1e-6f) * g[i] + be[i];
  of[(size_t)r * 256 + i] = y;
  if (ob) ob[(size_t)r * 256 + i] = f2b(y);
}

// ---------------- launch ----------------

extern "C" void kernel_launch(void* const* d_in, const int* in_sizes, int n_in,
                              void* d_out, int out_size, void* d_ws, size_t ws_size,
                              hipStream_t stream) {
  (void)in_sizes; (void)n_in; (void)out_size; (void)ws_size;
  const float* node = (const float*)d_in[0];
  const float* edge = (const float*)d_in[1];
  const float* Wq   = (const float*)d_in[2];
  const float* Wk   = (const float*)d_in[3];
  const float* Wv   = (const float*)d_in[4];
  const float* Wp   = (const float*)d_in[5];
  const float* bp   = (const float*)d_in[6];
  const float* g1   = (const float*)d_in[7];
  const float* be1  = (const float*)d_in[8];
  const float* W1   = (const float*)d_in[9];
  const float* b1   = (const float*)d_in[10];
  const float* W2   = (const float*)d_in[11];
  const float* b2   = (const float*)d_in[12];
  const float* g2   = (const float*)d_in[13];
  const float* be2  = (const float*)d_in[14];
  float* out = (float*)d_out;

  char* ws = (char*)d_ws;
  size_t off = 0;
  auto alloc = [&](size_t bytes) -> char* {
    char* p = ws + off;
    off = (off + bytes + 255) & ~(size_t)255;
    return p;
  };
  ushort* node_bf = (ushort*)alloc((size_t)R_ * D_ * 2);
  ushort* wqkvBig = (ushort*)alloc((size_t)2048 * 256 * 2);       // 1536 qkv + 512 qe cols
  ushort* wpT     = (ushort*)alloc((size_t)256 * 512 * 2);
  ushort* w1T     = (ushort*)alloc((size_t)1024 * 256 * 2);
  ushort* w2T     = (ushort*)alloc((size_t)256 * 1024 * 2);
  ushort* qkv     = (ushort*)alloc((size_t)R_ * 2048 * 2);        // 8 MiB (q|kn|v|qe)
  ushort* vt      = (ushort*)alloc((size_t)16 * 64 * 1024 * 2);   // 2 MiB
  __half* logits  = (__half*)alloc((size_t)16 * 1024 * 1024 * 2); // 32 MiB fp16
  ushort* attn    = (ushort*)alloc((size_t)16 * 1024 * 1024 * 2); // 32 MiB
  ushort* mo      = (ushort*)alloc((size_t)R_ * 512 * 2);
  float*  mha     = (float*) alloc((size_t)R_ * 256 * 4);
  float*  xf      = (float*) alloc((size_t)R_ * 256 * 4);
  ushort* xb      = (ushort*)alloc((size_t)R_ * 256 * 2);
  ushort* hb      = (ushort*)alloc((size_t)R_ * 1024 * 2);
  float*  ff      = (float*) alloc((size_t)R_ * 256 * 4);

  ushort* wqkvT = wqkvBig;                  // rows 0..1535
  ushort* wqeT  = wqkvBig + (size_t)1536 * 256;   // rows 1536..2047

  // --- single fused pack (node + all weights + Wqe pre-product) ---
  k_pack<<<dim3(6656), dim3(256), 0, stream>>>(node, Wq, Wk, Wv, Wp, W1, W2,
                                               node_bf, wqkvT, wpT, w1T, w2T, wqeT);

  // --- qkv|qe = node @ [Wqkv|Wqe]  (bf16 out, q & qe pre-scaled; N=2048) ---
  k_gemm<0, 1, 1><<<dim3(32, 32, 1), dim3(256), 0, stream>>>(
      node_bf, wqkvBig, qkv, nullptr, 2048, 2048, 256, 256, 256, 2048,
      0LL, 0LL, 0LL, 0LL, 0LL, 0LL);

  // --- vT pack (for attn@v B-panel) ---
  k_vT<<<dim3(4096), dim3(256), 0, stream>>>(qkv, vt);

  // --- node logits = q @ kn^T  (batched over (b,h); 64x256 tiles; fp16 out) ---
  k_gemm<0, 2, 4><<<dim3(16, 4, 16), dim3(256), 0, stream>>>(
      qkv, qkv + 512, logits, nullptr, 1024, 1024, 64, 2048, 2048, 1024,
      2097152LL, 64LL, 2097152LL, 64LL, 8388608LL, 1048576LL);

  // --- fused: edge MFMA dot + node logits + softmax -> bf16 attn ---
  k_fused<<<dim3(2048), dim3(256), 0, stream>>>(edge, qkv + 1536, 2048, logits, attn);

  // --- mo = attn @ v  (batched; Bt = vT; bf16 out as [b][n][h*64+o]) ---
  k_gemm<0, 1, 1><<<dim3(16, 1, 16), dim3(256), 0, stream>>>(
      attn, vt, mo, nullptr, 1024, 64, 1024, 1024, 1024, 512,
      8388608LL, 1048576LL, 524288LL, 65536LL, 524288LL, 64LL);

  // --- mha = mo @ Wp + bp  (fp32) ---
  k_gemm<2, 0, 1><<<dim3(32, 4, 1), dim3(256), 0, stream>>>(
      mo, wpT, mha, bp, 2048, 256, 512, 512, 512, 256,
      0LL, 0LL, 0LL, 0LL, 0LL, 0LL);

  // --- x = LN1(node + mha) -> xf (fp32), xb (bf16) ---
  k_ln<<<dim3(2048), dim3(256), 0, stream>>>(node, mha, g1, be1, xf, xb);

  // --- ffn hidden = relu(x @ W1 + b1)  (bf16) ---
  k_gemm<3, 1, 1><<<dim3(32, 16, 1), dim3(256), 0, stream>>>(
      xb, w1T, hb, b1, 2048, 1024, 256, 256, 256, 1024,
      0LL, 0LL, 0LL, 0LL, 0LL, 0LL);

  // --- ff = hidden @ W2 + b2  (fp32) ---
  k_gemm<2, 0, 1><<<dim3(32, 4, 1), dim3(256), 0, stream>>>(
      hb, w2T, ff, b2, 2048, 256, 1024, 1024, 1024, 256,
      0LL, 0LL, 0LL, 0LL, 0LL, 0LL);

  // --- out = LN2(x + ff)  (fp32 to d_out) ---
  k_ln<<<dim3(2048), dim3(256), 0, stream>>>(xf, ff, g2, be2, out, nullptr);
}

// Round 12
// 226.467 us; speedup vs baseline: 1.0618x; 1.0425x over previous
//
#include <hip/hip_runtime.h>
#include <hip/hip_bf16.h>
#include <hip/hip_fp16.h>

// Problem constants
#define B_  2
#define N_  1024
#define D_  256
#define E_  64
#define H_  8
#define HS_ 64
#define FF_ 1024
#define R_  (B_*N_)   // 2048 rows (b,n)

typedef short bf8 __attribute__((ext_vector_type(8)));   // 8 bf16 (bit pattern) = 4 VGPRs
typedef float f4  __attribute__((ext_vector_type(4)));

static __device__ __forceinline__ ushort f2b(float f) {
  __hip_bfloat16 h = __float2bfloat16(f);
  return *reinterpret_cast<ushort*>(&h);
}

static __device__ __forceinline__ ushort f2h(float f) {
  __half h = __float2half(f);
  return *reinterpret_cast<ushort*>(&h);
}

static __device__ __forceinline__ float h2f(ushort u) {
  __half h = *reinterpret_cast<__half*>(&u);
  return __half2float(h);
}

static __device__ __forceinline__ ushort4 f4_to_b4(float4 v) {
  ushort4 r;
  r.x = f2b(v.x); r.y = f2b(v.y); r.z = f2b(v.z); r.w = f2b(v.w);
  return r;
}

// ---------------- fused weight pack (all bf16, B-matrices TRANSPOSED [N][K]) ----------------
__global__ void k_pack(const float* __restrict__ node, const float* __restrict__ Wq,
                       const float* __restrict__ Wk, const float* __restrict__ Wv,
                       const float* __restrict__ Wp, const float* __restrict__ W1,
                       const float* __restrict__ W2,
                       ushort* __restrict__ node_bf, ushort* __restrict__ wqkvT,
                       ushort* __restrict__ wkeT, ushort* __restrict__ wpT,
                       ushort* __restrict__ w1T, ushort* __restrict__ w2T) {
  int idx = blockIdx.x * 256 + threadIdx.x;
  if (idx < 524288) {                       // node -> bf16
    node_bf[idx] = f2b(node[idx]);
    return;
  }
  idx -= 524288;
  if (idx < 393216) {                       // wqkvT[c][i], c in [0,1536), K=256
    int c = idx >> 8, i = idx & 255;
    int mat = c >> 9, h = (c >> 6) & 7, o = c & 63;
    float v;
    if (mat == 0)      v = Wq[(h * 256 + i) * 64 + o] * 0.125f;   // q scaled 1/sqrt(HS)
    else if (mat == 1) v = Wk[(h * 320 + i) * 64 + o];            // Wk: [H][320][64]
    else               v = Wv[(h * 256 + i) * 64 + o];
    wqkvT[idx] = f2b(v);
    return;
  }
  idx -= 393216;
  if (idx < 262144) {                       // wkeT[c=h2*64+e][r=h*64+o]  (block-diagonal)
    int c = idx >> 9, r = idx & 511;
    int h2 = c >> 6, e = c & 63, h = r >> 6, o = r & 63;
    wkeT[idx] = (h2 == h) ? f2b(Wk[(h * 320 + 256 + e) * 64 + o]) : (ushort)0;
    return;
  }
  idx -= 262144;
  if (idx < 131072) {                       // wpT[c][r], c in [0,256), r = h*64+i
    int c = idx >> 9, r = idx & 511;
    wpT[idx] = f2b(Wp[r * 256 + c]);
    return;
  }
  idx -= 131072;
  if (idx < 262144) {                       // w1T[c][k], c in [0,1024), K=256
    int c = idx >> 8, k = idx & 255;
    w1T[idx] = f2b(W1[k * 1024 + c]);
    return;
  }
  idx -= 262144;
  {                                         // w2T[c][k], c in [0,256), K=1024
    int c = idx >> 10, k = idx & 1023;
    w2T[idx] = f2b(W2[k * 256 + c]);
  }
}

// vT[b][h][o][m] <- qkv[(b*1024+m)*1536 + 1024 + h*64 + o]   (B^T panel for attn@v)
__global__ void k_vT(const ushort* __restrict__ qkv, ushort* __restrict__ vt) {
  int idx = blockIdx.x * 256 + threadIdx.x;   // 16*64*1024
  if (idx >= 16 * 64 * 1024) return;
  int m = idx & 1023;
  int rest = idx >> 10;
  int o = rest & 63;
  int bh = rest >> 6;
  int b = bh >> 3, h = bh & 7;
  vt[idx] = qkv[(size_t)(b * 1024 + m) * 1536 + 1024 + h * 64 + o];
}

// ---------------- generic bf16 MFMA GEMM, B pre-transposed ----------------
// C[M x N] = A[M x K] @ B[K x N];  Bt is B^T, row-major [N][K] with stride ldbt.
// EPI: 0=none, 2=+bias, 3=+bias,relu   OFMT: 0=f32, 1=bf16, 2=f16
// NBT: 64-col tiles per block (block = 64 x 64*NBT)
// BDIAG: B block-diagonal with 64x64 blocks -> K-loop restricted to [c0, c0+64)
// Batched via blockIdx.z: offset = (z>>3)*s1 + (z&7)*s2  (element offsets)
template<int EPI, int OFMT, int NBT, bool BDIAG>
__global__ void k_gemm(const ushort* __restrict__ A, const ushort* __restrict__ Bt,
                       void* __restrict__ Cv, const float* __restrict__ bias,
                       int M, int N, int K, int lda, int ldbt, int ldc,
                       long long as1, long long as2, long long bs1, long long bs2,
                       long long cs1, long long cs2) {
  int z = blockIdx.z;
  const ushort* Ab = A  + (size_t)((z >> 3) * as1 + (z & 7) * as2);
  const ushort* Bb = Bt + (size_t)((z >> 3) * bs1 + (z & 7) * bs2);
  size_t coff = (size_t)((z >> 3) * cs1 + (z & 7) * cs2);
  int r0 = blockIdx.x * 64, c0 = blockIdx.y * (64 * NBT);

  __shared__ ushort As[64][40];          // [row][k], +8 pad
  __shared__ ushort Bs[64 * NBT][40];    // [col][k], +8 pad

  int tid = threadIdx.x;
  int lane = tid & 63, w = tid >> 6;
  int wm = w >> 1, wn = w & 1;            // wave -> 32-row half x 32-col half
  int kg = lane >> 4, lr = lane & 15;

  f4 acc[2][2 * NBT] = {};

  int kbeg = BDIAG ? c0 : 0;
  int kend = BDIAG ? c0 + 64 : K;
  for (int k0 = kbeg; k0 < kend; k0 += 32) {
    __syncthreads();
    { // stage A tile 64x32 (one 16B load per thread)
      int row = tid >> 2, ch = tid & 3;
      *(int4*)&As[row][ch * 8] = *(const int4*)(Ab + (size_t)(r0 + row) * lda + k0 + ch * 8);
    }
    #pragma unroll
    for (int i = 0; i < NBT; ++i) { // stage Bt tile 64*NBT x 32
      int row = (tid >> 2) + 64 * i, ch = tid & 3;
      *(int4*)&Bs[row][ch * 8] = *(const int4*)(Bb + (size_t)(c0 + row) * ldbt + k0 + ch * 8);
    }
    __syncthreads();

    bf8 bfr[2 * NBT];
    #pragma unroll
    for (int nt = 0; nt < NBT; ++nt)
      #pragma unroll
      for (int cb = 0; cb < 2; ++cb)
        bfr[nt * 2 + cb] = *(const bf8*)&Bs[nt * 64 + wn * 32 + cb * 16 + lr][kg * 8];
    #pragma unroll
    for (int rb = 0; rb < 2; ++rb) {
      bf8 af = *(const bf8*)&As[wm * 32 + rb * 16 + lr][kg * 8];     // A: row=l&15, k=8*kg+j
      #pragma unroll
      for (int q = 0; q < 2 * NBT; ++q)
        acc[rb][q] = __builtin_amdgcn_mfma_f32_16x16x32_bf16(af, bfr[q], acc[rb][q], 0, 0, 0);
    }
  }

  float*  Cf = (float*)Cv;
  ushort* Cb = (ushort*)Cv;
  __half* Ch = (__half*)Cv;
  #pragma unroll
  for (int rb = 0; rb < 2; ++rb) {
    #pragma unroll
    for (int q = 0; q < 2 * NBT; ++q) {
      #pragma unroll
      for (int rr = 0; rr < 4; ++rr) {
        int row = r0 + wm * 32 + rb * 16 + kg * 4 + rr;   // D: col=l&15, row=4*kg+reg
        int col = c0 + (q >> 1) * 64 + wn * 32 + (q & 1) * 16 + lr;
        size_t ci = coff + (size_t)row * ldc + col;
        float v = acc[rb][q][rr];
        if (EPI >= 2) v += bias[col];
        if (EPI == 3) v = fmaxf(v, 0.0f);
        if (OFMT == 1)      Cb[ci] = f2b(v);
        else if (OFMT == 2) Ch[ci] = __float2half(v);
        else                Cf[ci] = v;
      }
    }
  }
}

// ---------------- fused edge-logits (MFMA) + node-logits + softmax -> bf16 attn ----------------
// lg layout [h][1032] fp16: MFMA epilogue packs 4 m's into one ds_write_b64;
// softmax ownership m = 4t+j -> ushort4 logN loads / attn stores / lg reads.
__global__ __launch_bounds__(256, 4) void k_fused(
    const float* __restrict__ edge, const float* __restrict__ qe,
    const __half* __restrict__ logN, ushort* __restrict__ attn) {
  int bid = blockIdx.x;            // b*1024 + n
  int b = bid >> 10, n = bid & 1023;
  int t = threadIdx.x;
  int lane = t & 63, w = t >> 6;
  int kg = lane >> 4, lr = lane & 15;

  __shared__ ushort As[128 * 64];  // 16 KB bf16 stage, slot^(row&7) swizzle
  __shared__ ushort lg[8][1032];   // block logits [h][m] fp16, +8 pad (16.5 KB)
  __shared__ float red[2][4][8];

  // ---- B fragments (qe row -> bf16), built once, kept in 8 VGPRs ----
  bf8 bq[2];
  {
    const float* qrow = qe + (size_t)bid * 512 + (size_t)(lr & 7) * 64;
    #pragma unroll
    for (int kk = 0; kk < 2; ++kk) {
      float4 a  = *reinterpret_cast<const float4*>(&qrow[kk * 32 + kg * 8]);
      float4 c4 = *reinterpret_cast<const float4*>(&qrow[kk * 32 + kg * 8 + 4]);
      bq[kk][0] = (short)f2b(a.x);  bq[kk][1] = (short)f2b(a.y);
      bq[kk][2] = (short)f2b(a.z);  bq[kk][3] = (short)f2b(a.w);
      bq[kk][4] = (short)f2b(c4.x); bq[kk][5] = (short)f2b(c4.y);
      bq[kk][6] = (short)f2b(c4.z); bq[kk][7] = (short)f2b(c4.w);
    }
  }

  const float* eb = edge + (size_t)bid * 65536;   // 1024 rows x 64 floats

  // prefetch tile 0 (8 float4/thread, fully coalesced)
  float4 pf[8];
  #pragma unroll
  for (int u = 0; u < 8; ++u)
    pf[u] = reinterpret_cast<const float4*>(eb)[t + 256 * u];

  #pragma unroll 1
  for (int tl = 0; tl < 8; ++tl) {
    __syncthreads();               // prev tile's A-frag reads done
    #pragma unroll
    for (int u = 0; u < 8; ++u) {  // cvt fp32->bf16, swizzled write: slot ^= row&7
      int g = t + 256 * u;
      int rl = g >> 4, c = t & 15;          // row 0..127, float4-slot 0..15
      int slot = (c >> 1) ^ (rl & 7), half = c & 1;
      *reinterpret_cast<ushort4*>(&As[rl * 64 + slot * 8 + half * 4]) = f4_to_b4(pf[u]);
    }
    if (tl < 7) {                  // issue next tile's loads; hide under compute
      const float4* src = reinterpret_cast<const float4*>(eb + (tl + 1) * 8192);
      #pragma unroll
      for (int u = 0; u < 8; ++u) pf[u] = src[t + 256 * u];
    }
    __syncthreads();               // stage visible

    // wave w owns stage rows [w*32, w*32+32): 2 sub-tiles of 16 m
    #pragma unroll
    for (int sub = 0; sub < 2; ++sub) {
      int sr = w * 32 + sub * 16 + lr;      // A row in stage
      f4 acc = {};
      #pragma unroll
      for (int kk = 0; kk < 2; ++kk) {
        bf8 af = *reinterpret_cast<const bf8*>(&As[sr * 64 + (((kk * 4 + kg) ^ (sr & 7)) << 3)]);
        acc = __builtin_amdgcn_mfma_f32_16x16x32_bf16(af, bq[kk], acc, 0, 0, 0);
      }
      if (lr < 8) {                         // D: col=l&15 (=h), row=4*kg+rr
        int mbase = tl * 128 + w * 32 + sub * 16 + kg * 4;
        uint2 pk;
        pk.x = (uint)f2h(acc[0]) | ((uint)f2h(acc[1]) << 16);
        pk.y = (uint)f2h(acc[2]) | ((uint)f2h(acc[3]) << 16);
        *reinterpret_cast<uint2*>(&lg[lr][mbase]) = pk;   // one 8B write for 4 m's
      }
    }
  }

  // issue node-logit loads BEFORE the barrier (ushort4 = 8B/lane, m = 4t..4t+3)
  ushort4 lNr[8];
  #pragma unroll
  for (int h = 0; h < 8; ++h)
    lNr[h] = *reinterpret_cast<const ushort4*>(
        &reinterpret_cast<const ushort*>(logN)[((size_t)(b * 8 + h) * 1024 + n) * 1024 + 4 * t]);
  __syncthreads();                 // lg complete

  // ---- softmax: thread owns m = 4t + j ----
  float l[4][8];
  #pragma unroll
  for (int h = 0; h < 8; ++h) {
    ushort4 lv = *reinterpret_cast<const ushort4*>(&lg[h][4 * t]);
    l[0][h] = h2f(lv.x) + h2f(lNr[h].x);
    l[1][h] = h2f(lv.y) + h2f(lNr[h].y);
    l[2][h] = h2f(lv.z) + h2f(lNr[h].z);
    l[3][h] = h2f(lv.w) + h2f(lNr[h].w);
  }
  float mx[8], sm[8];
  #pragma unroll
  for (int h = 0; h < 8; ++h) {
    float v = fmaxf(fmaxf(l[0][h], l[1][h]), fmaxf(l[2][h], l[3][h]));
    #pragma unroll
    for (int off = 32; off; off >>= 1) v = fmaxf(v, __shfl_xor(v, off));
    if (lane == 0) red[0][w][h] = v;
  }
  __syncthreads();
  #pragma unroll
  for (int h = 0; h < 8; ++h)
    mx[h] = fmaxf(fmaxf(red[0][0][h], red[0][1][h]), fmaxf(red[0][2][h], red[0][3][h]));
  #pragma unroll
  for (int j = 0; j < 4; ++j)
    #pragma unroll
    for (int h = 0; h < 8; ++h)
      l[j][h] = __expf(l[j][h] - mx[h]);
  #pragma unroll
  for (int h = 0; h < 8; ++h) {
    float v = l[0][h] + l[1][h] + l[2][h] + l[3][h];
    #pragma unroll
    for (int off = 32; off; off >>= 1) v += __shfl_xor(v, off);
    if (lane == 0) red[1][w][h] = v;
  }
  __syncthreads();
  #pragma unroll
  for (int h = 0; h < 8; ++h)
    sm[h] = 1.0f / (red[1][0][h] + red[1][1][h] + red[1][2][h] + red[1][3][h]);
  #pragma unroll
  for (int h = 0; h < 8; ++h) {
    size_t base = ((size_t)(b * 8 + h) * 1024 + n) * 1024;
    ushort4 o;
    o.x = f2b(l[0][h] * sm[h]);
    o.y = f2b(l[1][h] * sm[h]);
    o.z = f2b(l[2][h] * sm[h]);
    o.w = f2b(l[3][h] * sm[h]);
    *reinterpret_cast<ushort4*>(&attn[base + 4 * t]) = o;   // 8B/lane store
  }
}

// ---------------- residual + layernorm (D=256, one block per row) ----------------
__global__ void k_ln(const float* __restrict__ a, const float* __restrict__ bb,
                     const float* __restrict__ g, const float* __restrict__ be,
                     float* __restrict__ of, ushort* __restrict__ ob) {
  int r = blockIdx.x, i = threadIdx.x;
  float t = a[(size_t)r * 256 + i] + bb[(size_t)r * 256 + i];
  __shared__ float red[4];

  float s = t;
  for (int off = 32; off; off >>= 1) s += __shfl_xor(s, off);
  if ((i & 63) == 0) red[i >> 6] = s;
  __syncthreads();
  float mean = (red[0] + red[1] + red[2] + red[3]) * (1.0f / 256.0f);
  __syncthreads();

  float d = t - mean;
  float q = d * d;
  for (int off = 32; off; off >>= 1) q += __shfl_xor(q, off);
  if ((i & 63) == 0) red[i >> 6] = q;
  __syncthreads();
  float var = (red[0] + red[1] + red[2] + red[3]) * (1.0f / 256.0f);

  float y = d * rsqrtf(var + 1e-6f) * g[i] + be[i];
  of[(size_t)r * 256 + i] = y;
  if (ob) ob[(size_t)r * 256 + i] = f2b(y);
}

// ---------------- launch ----------------

extern "C" void kernel_launch(void* const* d_in, const int* in_sizes, int n_in,
                              void* d_out, int out_size, void* d_ws, size_t ws_size,
                              hipStream_t stream) {
  (void)in_sizes; (void)n_in; (void)out_size; (void)ws_size;
  const float* node = (const float*)d_in[0];
  const float* edge = (const float*)d_in[1];
  const float* Wq   = (const float*)d_in[2];
  const float* Wk   = (const float*)d_in[3];
  const float* Wv   = (const float*)d_in[4];
  const float* Wp   = (const float*)d_in[5];
  const float* bp   = (const float*)d_in[6];
  const float* g1   = (const float*)d_in[7];
  const float* be1  = (const float*)d_in[8];
  const float* W1   = (const float*)d_in[9];
  const float* b1   = (const float*)d_in[10];
  const float* W2   = (const float*)d_in[11];
  const float* b2   = (const float*)d_in[12];
  const float* g2   = (const float*)d_in[13];
  const float* be2  = (const float*)d_in[14];
  float* out = (float*)d_out;

  char* ws = (char*)d_ws;
  size_t off = 0;
  auto alloc = [&](size_t bytes) -> char* {
    char* p = ws + off;
    off = (off + bytes + 255) & ~(size_t)255;
    return p;
  };
  ushort* node_bf = (ushort*)alloc((size_t)R_ * D_ * 2);
  ushort* wqkvT   = (ushort*)alloc((size_t)1536 * 256 * 2);
  ushort* wkeT    = (ushort*)alloc((size_t)512 * 512 * 2);
  ushort* wpT     = (ushort*)alloc((size_t)256 * 512 * 2);
  ushort* w1T     = (ushort*)alloc((size_t)1024 * 256 * 2);
  ushort* w2T     = (ushort*)alloc((size_t)256 * 1024 * 2);
  ushort* qkv     = (ushort*)alloc((size_t)R_ * 1536 * 2);        // 6 MiB
  float*  qe      = (float*) alloc((size_t)R_ * 512 * 4);         // 4 MiB
  ushort* vt      = (ushort*)alloc((size_t)16 * 64 * 1024 * 2);   // 2 MiB
  __half* logits  = (__half*)alloc((size_t)16 * 1024 * 1024 * 2); // 32 MiB fp16
  ushort* attn    = (ushort*)alloc((size_t)16 * 1024 * 1024 * 2); // 32 MiB
  ushort* mo      = (ushort*)alloc((size_t)R_ * 512 * 2);
  float*  mha     = (float*) alloc((size_t)R_ * 256 * 4);
  float*  xf      = (float*) alloc((size_t)R_ * 256 * 4);
  ushort* xb      = (ushort*)alloc((size_t)R_ * 256 * 2);
  ushort* hb      = (ushort*)alloc((size_t)R_ * 1024 * 2);
  float*  ff      = (float*) alloc((size_t)R_ * 256 * 4);

  // --- single fused pack ---
  k_pack<<<dim3(7168), dim3(256), 0, stream>>>(node, Wq, Wk, Wv, Wp, W1, W2,
                                               node_bf, wqkvT, wkeT, wpT, w1T, w2T);

  // --- qkv = node @ Wqkv (bf16 out, q pre-scaled) ---
  k_gemm<0, 1, 1, false><<<dim3(32, 24, 1), dim3(256), 0, stream>>>(
      node_bf, wqkvT, qkv, nullptr, 2048, 1536, 256, 256, 256, 1536,
      0LL, 0LL, 0LL, 0LL, 0LL, 0LL);

  // --- qe = q @ blockdiag(WkE^T)  (fp32 out; BDIAG skips the zero K-blocks) ---
  k_gemm<0, 0, 1, true><<<dim3(32, 8, 1), dim3(256), 0, stream>>>(
      qkv, wkeT, qe, nullptr, 2048, 512, 512, 1536, 512, 512,
      0LL, 0LL, 0LL, 0LL, 0LL, 0LL);

  // --- vT pack (for attn@v B-panel) ---
  k_vT<<<dim3(4096), dim3(256), 0, stream>>>(qkv, vt);

  // --- node logits = q @ kn^T  (batched over (b,h); 64x256 tiles; fp16 out) ---
  k_gemm<0, 2, 4, false><<<dim3(16, 4, 16), dim3(256), 0, stream>>>(
      qkv, qkv + 512, logits, nullptr, 1024, 1024, 64, 1536, 1536, 1024,
      1572864LL, 64LL, 1572864LL, 64LL, 8388608LL, 1048576LL);

  // --- fused: edge MFMA dot + node logits + softmax -> bf16 attn ---
  k_fused<<<dim3(2048), dim3(256), 0, stream>>>(edge, qe, logits, attn);

  // --- mo = attn @ v  (batched; Bt = vT; bf16 out as [b][n][h*64+o]) ---
  k_gemm<0, 1, 1, false><<<dim3(16, 1, 16), dim3(256), 0, stream>>>(
      attn, vt, mo, nullptr, 1024, 64, 1024, 1024, 1024, 512,
      8388608LL, 1048576LL, 524288LL, 65536LL, 524288LL, 64LL);

  // --- mha = mo @ Wp + bp  (fp32) ---
  k_gemm<2, 0, 1, false><<<dim3(32, 4, 1), dim3(256), 0, stream>>>(
      mo, wpT, mha, bp, 2048, 256, 512, 512, 512, 256,
      0LL, 0LL, 0LL, 0LL, 0LL, 0LL);

  // --- x = LN1(node + mha) -> xf (fp32), xb (bf16) ---
  k_ln<<<dim3(2048), dim3(256), 0, stream>>>(node, mha, g1, be1, xf, xb);

  // --- ffn hidden = relu(x @ W1 + b1)  (bf16) ---
  k_gemm<3, 1, 1, false><<<dim3(32, 16, 1), dim3(256), 0, stream>>>(
      xb, w1T, hb, b1, 2048, 1024, 256, 256, 256, 1024,
      0LL, 0LL, 0LL, 0LL, 0LL, 0LL);

  // --- ff = hidden @ W2 + b2  (fp32) ---
  k_gemm<2, 0, 1, false><<<dim3(32, 4, 1), dim3(256), 0, stream>>>(
      hb, w2T, ff, b2, 2048, 256, 1024, 1024, 1024, 256,
      0LL, 0LL, 0LL, 0LL, 0LL, 0LL);

  // --- out = LN2(x + ff)  (fp32 to d_out) ---
  k_ln<<<dim3(2048), dim3(256), 0, stream>>>(xf, ff, g2, be2, out, nullptr);
}